// Round 9
// baseline (1764.960 us; speedup 1.0000x reference)
//
#include <hip/hip_runtime.h>
#include <math.h>

// Problem constants
#define DD   256
#define TTT  512
#define JJJ  128
#define BBB  32
#define NC   1536     // 6*D combined gate columns (fwd 0..767, bwd 768..1535)
#define ROWS_ALL 36864

typedef _Float16 v2h __attribute__((ext_vector_type(2)));
typedef _Float16 v4h __attribute__((ext_vector_type(4)));
typedef _Float16 v8h __attribute__((ext_vector_type(8)));
typedef short short8 __attribute__((ext_vector_type(8)));
typedef float f32x4 __attribute__((ext_vector_type(4)));

__device__ __forceinline__ short f2bf(float f) {
    unsigned u = __float_as_uint(f);
    unsigned r = (u + 0x7FFFu + ((u >> 16) & 1u)) >> 16;   // RNE
    return (short)r;
}

// ---------------------------------------------------------------------------
// K0: prep — token table, wh16 (fp16 c-major whh concat), biases, Bt bf16, w2h
// ---------------------------------------------------------------------------
__global__ __launch_bounds__(256) void prep_kernel(
    const int* __restrict__ cmnt, const int* __restrict__ src_tok, const int* __restrict__ tgt_tok,
    const float* __restrict__ wih_f, const float* __restrict__ wih_b,
    const float* __restrict__ whh_f, const float* __restrict__ whh_b,
    const float* __restrict__ bih_f, const float* __restrict__ bih_b,
    const float* __restrict__ bhh_f, const float* __restrict__ bhh_b,
    const float* __restrict__ w2,
    int* __restrict__ tok_all, _Float16* __restrict__ wh16,
    float* __restrict__ bihc, float* __restrict__ bhhc, short* __restrict__ Bt,
    _Float16* __restrict__ w2h)
{
    const int idx = blockIdx.x * blockDim.x + threadIdx.x;
    const int stride = gridDim.x * blockDim.x;
    for (int i = idx; i < ROWS_ALL; i += stride)
        tok_all[i] = (i < 16384) ? src_tok[i] : (i < 32768) ? tgt_tok[i - 16384] : cmnt[i - 32768];
    // wh16[c][k], c-major k-contig (torch whh layout is already (3D, D) row-major)
    for (int i = idx; i < 393216; i += stride)
        wh16[i] = (_Float16)(i < 196608 ? whh_f[i] : whh_b[i - 196608]);
    for (int i = idx; i < 393216; i += stride)
        Bt[i] = f2bf(i < 196608 ? wih_f[i] : wih_b[i - 196608]);
    for (int i = idx; i < NC; i += stride) {
        bihc[i] = (i < 768) ? bih_f[i] : bih_b[i - 768];
        bhhc[i] = (i < 768) ? bhh_f[i] : bhh_b[i - 768];
    }
    for (int i = idx; i < 512; i += stride)
        w2h[i] = (_Float16)w2[i];
}

// K0b: gather token embedding rows to bf16 A matrix (nrows x 256)
__global__ __launch_bounds__(256) void gatherA_kernel(
    const int* __restrict__ tok, int nrows,
    const float* __restrict__ emb, short* __restrict__ A)
{
    const int idx = blockIdx.x * blockDim.x + threadIdx.x;
    const int stride = gridDim.x * blockDim.x;
    const int ngroups = nrows * 64;
    for (int g = idx; g < ngroups; g += stride) {
        const int i = g >> 6;
        const int kq = (g & 63) << 2;
        const float4 v = *(const float4*)(emb + (size_t)tok[i] * 256 + kq);
        short4 s;
        s.x = f2bf(v.x); s.y = f2bf(v.y); s.z = f2bf(v.z); s.w = f2bf(v.w);
        *(short4*)(A + (size_t)i * 256 + kq) = s;
    }
}

// ---------------------------------------------------------------------------
// K1: gi GEMM via bf16 MFMA 16x16x32, LDS-staged; epilogue writes SWIZZLED
// fp16 gi: gi_swz[tslot][dir][bhalf][lane512][24], idx24 = g*8 + u*4 + reg,
// so each gru lane reads its 24 step-values as 48 contiguous bytes.
// bhh_r / bhh_z folded into the bias here (g<2); bhh_n stays in gru (mult by r).
// ---------------------------------------------------------------------------
#define LP 40   // padded LDS row pitch in 2-byte units
__global__ __launch_bounds__(256) void gi_mfma(
    const short* __restrict__ A, const short* __restrict__ Bt,
    const float* __restrict__ bihc, const float* __restrict__ bhhc,
    _Float16* __restrict__ gi_swz)
{
    __shared__ __align__(16) short As[128 * LP];
    __shared__ __align__(16) short Bs[128 * LP];
    const int tid = threadIdx.x;
    const int wave = tid >> 6, lane = tid & 63;
    const int quad = lane >> 4, l16 = lane & 15;
    const int m0 = blockIdx.x * 128, n0 = blockIdx.y * 128;
    const int wm = (wave & 1) * 64, wn = (wave >> 1) * 64;

    const int sr = tid >> 2;
    const int sk = (tid & 3) * 8;
    const short* ga0 = A  + (size_t)(m0 + sr) * 256 + sk;
    const short* ga1 = A  + (size_t)(m0 + sr + 64) * 256 + sk;
    const short* gb0 = Bt + (size_t)(n0 + sr) * 256 + sk;
    const short* gb1 = Bt + (size_t)(n0 + sr + 64) * 256 + sk;

    f32x4 acc[4][4];
    #pragma unroll
    for (int i = 0; i < 4; ++i)
        #pragma unroll
        for (int j = 0; j < 4; ++j) acc[i][j] = (f32x4){0.f, 0.f, 0.f, 0.f};

    for (int k0 = 0; k0 < 256; k0 += 32) {
        const short8 a0 = *(const short8*)(ga0 + k0);
        const short8 a1 = *(const short8*)(ga1 + k0);
        const short8 b0 = *(const short8*)(gb0 + k0);
        const short8 b1 = *(const short8*)(gb1 + k0);
        __syncthreads();
        *(short8*)&As[sr * LP + sk] = a0;
        *(short8*)&As[(sr + 64) * LP + sk] = a1;
        *(short8*)&Bs[sr * LP + sk] = b0;
        *(short8*)&Bs[(sr + 64) * LP + sk] = b1;
        __syncthreads();
        short8 af[4], bf[4];
        #pragma unroll
        for (int i = 0; i < 4; ++i)
            af[i] = *(const short8*)&As[(wm + i * 16 + l16) * LP + quad * 8];
        #pragma unroll
        for (int j = 0; j < 4; ++j)
            bf[j] = *(const short8*)&Bs[(wn + j * 16 + l16) * LP + quad * 8];
        #pragma unroll
        for (int i = 0; i < 4; ++i)
            #pragma unroll
            for (int j = 0; j < 4; ++j)
                acc[i][j] = __builtin_amdgcn_mfma_f32_16x16x32_bf16(af[i], bf[j], acc[i][j], 0, 0, 0);
    }

    // --- swizzled epilogue ---
    const int seq = (m0 >= 32768) ? 2 : (m0 >= 16384 ? 1 : 0);
    const int rowbase = seq * 16384;
    const int logT = (seq == 2) ? 7 : 9;
    const int tmask = (1 << logT) - 1;
    const int seqTbase = (seq == 0) ? 0 : (seq == 1) ? 512 : 1024;

    int colpart[4];
    float bias[4];
    #pragma unroll
    for (int jj = 0; jj < 4; ++jj) {
        const int c = n0 + wn + jj * 16 + l16;
        const int dir = (c >= 768) ? 1 : 0;
        const int cg = c - dir * 768;
        const int g = cg >> 8;
        const int jloc = cg & 255;
        colpart[jj] = dir * 24576 + (jloc >> 5) * 1536 + (jloc & 15) * 24
                      + g * 8 + ((jloc >> 4) & 1) * 4;
        bias[jj] = bihc[c] + ((g < 2) ? bhhc[c] : 0.f);
    }
    #pragma unroll
    for (int i = 0; i < 4; ++i) {
        #pragma unroll
        for (int reg = 0; reg < 4; ++reg) {
            const int rowloc = m0 + wm + i * 16 + quad * 4 + reg - rowbase;
            const int b = rowloc >> logT;
            const int t = rowloc & tmask;
            const size_t rowpart = (size_t)(seqTbase + t) * 49152
                                   + (b >> 4) * 12288 + ((b >> 2) & 3) * 384 + (b & 3);
            #pragma unroll
            for (int jj = 0; jj < 4; ++jj)
                gi_swz[rowpart + colpart[jj]] = (_Float16)(acc[i][jj][reg] + bias[jj]);
        }
    }
}

// ---------------------------------------------------------------------------
// K2: GRU recurrence via f16 MFMA across the batch dimension.
// 12 blocks = (chain 0..5) x (bhalf 0..1); 512 thr = 8 waves (2/SIMD).
// Per step: S[16 x 768] = h[16 x 256] @ whh^T via 48 MFMAs/wave
// (wave w owns 32 j-cols x 3 gates = 6 n-tiles; weights 48 v8h resident —
// MFMA reads A/B from AGPR natively, no move penalty). Gates in-register
// (C-layout lane owns 8 (b,j) pairs; h_prev in regs). h double-buffered in
// LDS (pitch 264: <=2-way banks) -> ONE barrier/step. e-store delayed 1 step.
// ---------------------------------------------------------------------------
__global__ __launch_bounds__(512, 2) void gru_kernel(
    const _Float16* __restrict__ gi_swz, const _Float16* __restrict__ wh16,
    const float* __restrict__ bhhc,
    _Float16* __restrict__ e_src, _Float16* __restrict__ e_tgt, _Float16* __restrict__ e_cmnt)
{
    const int chain = (int)(blockIdx.x >> 1);
    const int bhalf = (int)(blockIdx.x & 1);
    const int seq = chain >> 1, dir = chain & 1;
    const int Tlen = (seq == 2) ? JJJ : TTT;
    const int seqTbase = (seq == 0) ? 0 : (seq == 1) ? 512 : 1024;
    _Float16* e = (seq == 0) ? e_src : (seq == 1) ? e_tgt : e_cmnt;
    const int cb = dir * 768;

    const int tid = threadIdx.x;
    const int w = tid >> 6, lane = tid & 63;
    const int quad = lane >> 4, l16 = lane & 15;
    const int j0 = w * 32;

    __shared__ __align__(16) _Float16 hbuf[2][16 * 264];

    // Resident weights: 48 B-frags (v8h). Wf[g][u][ks] covers
    // n = cb + g*256 + j0 + u*16 + l16, k = ks*32 + quad*8 .. +7.
    v8h Wf[3][2][8];
    #pragma unroll
    for (int g = 0; g < 3; ++g)
        #pragma unroll
        for (int u = 0; u < 2; ++u) {
            const _Float16* wrow = wh16 + (size_t)(cb + g * 256 + j0 + u * 16 + l16) * 256 + quad * 8;
            #pragma unroll
            for (int ks = 0; ks < 8; ++ks)
                Wf[g][u][ks] = *(const v8h*)(wrow + ks * 32);
        }

    float bhn[2];
    #pragma unroll
    for (int u = 0; u < 2; ++u) bhn[u] = bhhc[cb + 512 + j0 + u * 16 + l16];

    float hp[2][4];
    #pragma unroll
    for (int u = 0; u < 2; ++u)
        #pragma unroll
        for (int reg = 0; reg < 4; ++reg) hp[u][reg] = 0.f;

    for (int i = tid; i < 16 * 264; i += 512) hbuf[0][i] = (_Float16)0.f;
    __syncthreads();

    // gi pointer: ((tslot*4 + dir*2 + bhalf)*512 + tid)*24 halfs
    const int t0 = dir ? (Tlen - 1) : 0;
    const _Float16* gp = gi_swz
        + ((size_t)(seqTbase + t0) * 2048 + (size_t)(dir * 1024 + bhalf * 512 + tid)) * 24;
    const long gistep = (dir ? -1L : 1L) * 49152;

    // e pointer for (reg=0, u=0): lane's stores at + reg*(Tlen*512) + u*16
    _Float16* ecur = e + ((size_t)(bhalf * 16 + quad * 4) * Tlen + t0) * 512 + dir * 256 + j0 + l16;
    const long estep = (dir ? -1L : 1L) * 512;
    const long eregstride = (long)Tlen * 512;
    _Float16* epend = ecur;

    for (int s = 0; s < Tlen; ++s) {
        // prefetch gi for this t (3x dwordx4), consumed after the k-loop
        const v8h g0 = *(const v8h*)(gp);
        const v8h g1 = *(const v8h*)(gp + 8);
        const v8h g2 = *(const v8h*)(gp + 16);
        // delayed e-store of h(t_prev): drains under the k-loop
        if (s > 0) {
            #pragma unroll
            for (int u = 0; u < 2; ++u)
                #pragma unroll
                for (int reg = 0; reg < 4; ++reg)
                    epend[(long)reg * eregstride + u * 16] = (_Float16)hp[u][reg];
        }

        f32x4 acc[3][2];
        #pragma unroll
        for (int g = 0; g < 3; ++g)
            #pragma unroll
            for (int u = 0; u < 2; ++u) acc[g][u] = (f32x4){0.f, 0.f, 0.f, 0.f};

        const _Float16* hb = &hbuf[s & 1][l16 * 264 + quad * 8];
        #pragma unroll
        for (int ks = 0; ks < 8; ++ks) {
            const v8h Af = *(const v8h*)(hb + ks * 32);
            #pragma unroll
            for (int g = 0; g < 3; ++g)
                #pragma unroll
                for (int u = 0; u < 2; ++u)
                    acc[g][u] = __builtin_amdgcn_mfma_f32_16x16x32_f16(Af, Wf[g][u][ks], acc[g][u], 0, 0, 0);
        }

        // gate math in-register; C-layout: col=l16 (j), row=quad*4+reg (b)
        _Float16* hw = &hbuf[(s + 1) & 1][(quad * 4) * 264 + j0 + l16];
        #pragma unroll
        for (int u = 0; u < 2; ++u) {
            #pragma unroll
            for (int reg = 0; reg < 4; ++reg) {
                const float gr = acc[0][u][reg] + (float)g0[u * 4 + reg];
                const float gz = acc[1][u][reg] + (float)g1[u * 4 + reg];
                const float r = 1.f / (1.f + __expf(-gr));
                const float z = 1.f / (1.f + __expf(-gz));
                const float x = (float)g2[u * 4 + reg] + r * (acc[2][u][reg] + bhn[u]);
                const float ex = __expf(2.f * x);
                const float n = 1.f - 2.f / (ex + 1.f);        // tanh(x)
                const float hnew = (1.f - z) * n + z * hp[u][reg];
                hp[u][reg] = hnew;
                hw[reg * 264 + u * 16] = (_Float16)hnew;
            }
        }
        epend = ecur;
        ecur += estep;
        gp += gistep;
        __syncthreads();        // hbuf[(s+1)&1] writes visible for next step
    }
    // flush last pending e-store
    #pragma unroll
    for (int u = 0; u < 2; ++u)
        #pragma unroll
        for (int reg = 0; reg < 4; ++reg)
            epend[(long)reg * eregstride + u * 16] = (_Float16)hp[u][reg];
}

// ---------------------------------------------------------------------------
// K3: sim via f16 MFMA 16x16x32.  S[b,t,j] = sum_d (ctx*w2)[t,d]*ec[j,d] + act
// Per (seq,b): M=512(t) in 4 tiles of 128, N=128(j), K=512.
// ---------------------------------------------------------------------------
__global__ __launch_bounds__(256) void sim_mfma(
    const _Float16* __restrict__ e_src, const _Float16* __restrict__ e_tgt,
    const _Float16* __restrict__ e_cmnt, const _Float16* __restrict__ w2h,
    const float* __restrict__ w2,
    const int* __restrict__ src_action, const int* __restrict__ tgt_action,
    float* __restrict__ S, float* __restrict__ rowmaxP)
{
    const int sb = (int)blockIdx.z;
    const int seq = sb >> 5, b = sb & 31;
    const int t0 = blockIdx.x * 128;
    const _Float16* ctx = ((seq == 0) ? e_src : e_tgt) + (size_t)b * 512 * 512;
    const _Float16* ec = e_cmnt + (size_t)b * 128 * 512;
    const int* act = (seq == 0) ? src_action : tgt_action;

    __shared__ __align__(16) _Float16 As[128 * LP];
    __shared__ __align__(16) _Float16 Bs[128 * LP];
    const int tid = threadIdx.x;
    const int wave = tid >> 6, lane = tid & 63;
    const int quad = lane >> 4, l16 = lane & 15;
    const int wm = (wave & 1) * 64, wn = (wave >> 1) * 64;
    const int sr = tid >> 2;
    const int sk = (tid & 3) * 8;

    const _Float16* ga0 = ctx + (size_t)(t0 + sr) * 512 + sk;
    const _Float16* ga1 = ctx + (size_t)(t0 + sr + 64) * 512 + sk;
    const _Float16* gb0 = ec + (size_t)sr * 512 + sk;
    const _Float16* gb1 = ec + (size_t)(sr + 64) * 512 + sk;

    f32x4 acc[4][4];
    #pragma unroll
    for (int i = 0; i < 4; ++i)
        #pragma unroll
        for (int j = 0; j < 4; ++j) acc[i][j] = (f32x4){0.f, 0.f, 0.f, 0.f};

    for (int k0 = 0; k0 < 512; k0 += 32) {
        v8h a0 = *(const v8h*)(ga0 + k0);
        v8h a1 = *(const v8h*)(ga1 + k0);
        const v8h b0 = *(const v8h*)(gb0 + k0);
        const v8h b1 = *(const v8h*)(gb1 + k0);
        const v8h w8 = *(const v8h*)(w2h + k0 + sk);
        a0 = a0 * w8;
        a1 = a1 * w8;
        __syncthreads();
        *(v8h*)&As[sr * LP + sk] = a0;
        *(v8h*)&As[(sr + 64) * LP + sk] = a1;
        *(v8h*)&Bs[sr * LP + sk] = b0;
        *(v8h*)&Bs[(sr + 64) * LP + sk] = b1;
        __syncthreads();
        v8h af[4], bf[4];
        #pragma unroll
        for (int i = 0; i < 4; ++i)
            af[i] = *(const v8h*)&As[(wm + i * 16 + l16) * LP + quad * 8];
        #pragma unroll
        for (int j = 0; j < 4; ++j)
            bf[j] = *(const v8h*)&Bs[(wn + j * 16 + l16) * LP + quad * 8];
        #pragma unroll
        for (int i = 0; i < 4; ++i)
            #pragma unroll
            for (int j = 0; j < 4; ++j)
                acc[i][j] = __builtin_amdgcn_mfma_f32_16x16x32_f16(af[i], bf[j], acc[i][j], 0, 0, 0);
    }

    const float w2a = w2[512];
    #pragma unroll
    for (int i = 0; i < 4; ++i) {
        #pragma unroll
        for (int reg = 0; reg < 4; ++reg) {
            const int t = t0 + wm + i * 16 + quad * 4 + reg;
            const float aterm = (float)act[b * 512 + t] * w2a;
            float m = -1e30f;
            #pragma unroll
            for (int j = 0; j < 4; ++j) {
                const float v = acc[i][j][reg] + aterm;
                S[((size_t)(sb * 512 + t)) * 128 + wn + j * 16 + l16] = v;
                m = fmaxf(m, v);
            }
            m = fmaxf(m, __shfl_xor(m, 1));
            m = fmaxf(m, __shfl_xor(m, 2));
            m = fmaxf(m, __shfl_xor(m, 4));
            m = fmaxf(m, __shfl_xor(m, 8));
            if (l16 == 0)
                rowmaxP[(size_t)(wave >> 1) * 32768 + sb * 512 + t] = m;
        }
    }
}

// K5: softmax over t (512) per (seq,b); combines the 2 j-tile max partials
__global__ __launch_bounds__(256) void softmax_kernel(const float* __restrict__ rowmaxP, float* __restrict__ bw)
{
    const int base = blockIdx.x * 512;
    const int tid = threadIdx.x;
    __shared__ float red[256];
    const float v0 = fmaxf(rowmaxP[base + tid], rowmaxP[32768 + base + tid]);
    const float v1 = fmaxf(rowmaxP[base + 256 + tid], rowmaxP[32768 + base + 256 + tid]);
    red[tid] = fmaxf(v0, v1);
    __syncthreads();
    for (int off = 128; off > 0; off >>= 1) {
        if (tid < off) red[tid] = fmaxf(red[tid], red[tid + off]);
        __syncthreads();
    }
    const float M = red[0];
    __syncthreads();
    const float e0 = __expf(v0 - M), e1 = __expf(v1 - M);
    red[tid] = e0 + e1;
    __syncthreads();
    for (int off = 128; off > 0; off >>= 1) {
        if (tid < off) red[tid] += red[tid + off];
        __syncthreads();
    }
    const float inv = 1.f / red[0];
    bw[base + tid] = e0 * inv;
    bw[base + 256 + tid] = e1 * inv;
}

// K6: outSP[c][sb*128+j] = sum_{t in chunk c} bw[sb,t] * S[sb,t,j]
__global__ __launch_bounds__(256) void weighted_kernel(
    const float* __restrict__ S, const float* __restrict__ bw, float* __restrict__ outSP)
{
    const int sb = blockIdx.x;
    const int ch = blockIdx.y;
    const int tid = threadIdx.x;
    const int j = tid & 127, half = tid >> 7;
    const float* Sb = S + (size_t)sb * 512 * 128;
    const float* w = bw + sb * 512;
    const int tb = ch * 64 + half * 32;
    float acc = 0.f;
    for (int t = tb; t < tb + 32; ++t)
        acc = fmaf(w[t], Sb[(size_t)t * 128 + j], acc);
    __shared__ float red[256];
    red[tid] = acc;
    __syncthreads();
    if (half == 0) outSP[(size_t)ch * 8192 + sb * 128 + j] = red[j] + red[128 + j];
}

// K7: sum chunk partials; write S_diff and result into d_out
__global__ __launch_bounds__(256) void final_kernel(
    const float* __restrict__ outSP, const float* __restrict__ rank_w,
    const float* __restrict__ rank_b, float* __restrict__ out)
{
    __shared__ float sArr[8192];
    const int tid = threadIdx.x;
    for (int q = tid; q < 8192; q += 256) {
        float s = 0.f;
        #pragma unroll
        for (int c = 0; c < 8; ++c) s += outSP[(size_t)c * 8192 + q];
        sArr[q] = s;
    }
    __syncthreads();
    for (int q = tid; q < 8192; q += 256) {
        const int b = q >> 8, c = q & 255;
        out[32 + q] = (c < 128) ? sArr[b * 128 + c] : sArr[4096 + b * 128 + (c - 128)];
    }
    if (tid < 32) {
        float acc = rank_b[0];
        for (int c = 0; c < 128; ++c) acc = fmaf(sArr[tid * 128 + c], rank_w[c], acc);
        for (int c = 0; c < 128; ++c) acc = fmaf(sArr[4096 + tid * 128 + c], rank_w[128 + c], acc);
        out[tid] = acc;
    }
}

// ---------------------------------------------------------------------------
extern "C" void kernel_launch(void* const* d_in, const int* in_sizes, int n_in,
                              void* d_out, int out_size, void* d_ws, size_t ws_size,
                              hipStream_t stream)
{
    const int* cmnt       = (const int*)d_in[0];
    const int* src_token  = (const int*)d_in[1];
    const int* tgt_token  = (const int*)d_in[2];
    const int* src_action = (const int*)d_in[3];
    const int* tgt_action = (const int*)d_in[4];
    const float* emb    = (const float*)d_in[5];
    const float* wih_f  = (const float*)d_in[6];
    const float* whh_f  = (const float*)d_in[7];
    const float* bih_f  = (const float*)d_in[8];
    const float* bhh_f  = (const float*)d_in[9];
    const float* wih_b  = (const float*)d_in[10];
    const float* whh_b  = (const float*)d_in[11];
    const float* bih_b  = (const float*)d_in[12];
    const float* bhh_b  = (const float*)d_in[13];
    const float* w2     = (const float*)d_in[14];
    const float* rank_w = (const float*)d_in[15];
    const float* rank_b = (const float*)d_in[16];
    float* out = (float*)d_out;

    // Workspace layout (units: fp32 slots). Proven tier-A fit since R6.
    float* ws = (float*)d_ws;
    size_t off = 0;
    int*   tok_all = (int*)(ws + off); off += 36864;
    short* Bt_bf16 = (short*)(ws + off); off += 196608;        // 1536x256 bf16
    _Float16* wh16 = (_Float16*)(ws + off); off += 196608;     // 1536x256 fp16
    float* bihc   = ws + off; off += 1536;
    float* bhhc   = ws + off; off += 1536;
    _Float16* w2h = (_Float16*)(ws + off); off += 256;
    float* rowmaxP = ws + off; off += 65536;
    float* bw     = ws + off; off += 32768;
    float* outSP  = ws + off; off += 65536;
    _Float16* e_src  = (_Float16*)(ws + off); off += 4194304;  // 8.4M halfs
    _Float16* e_tgt  = (_Float16*)(ws + off); off += 4194304;
    _Float16* e_cmnt = (_Float16*)(ws + off); off += 1048576;
    float* S      = ws + off; off += 4194304;
    _Float16* gi_swz = (_Float16*)(ws + off);                  // 56.6M halfs

    hipLaunchKernelGGL(prep_kernel, dim3(512), dim3(256), 0, stream,
        cmnt, src_token, tgt_token, wih_f, wih_b, whh_f, whh_b,
        bih_f, bih_b, bhh_f, bhh_b, w2, tok_all, wh16, bihc, bhhc, Bt_bf16, w2h);

    // A_bf16 (36864x256 shorts) aliases e_src+e_tgt, consumed before gru writes e.
    short* A = (short*)e_src;
    hipLaunchKernelGGL(gatherA_kernel, dim3(4096), dim3(256), 0, stream,
        tok_all, 36864, emb, A);
    hipLaunchKernelGGL(gi_mfma, dim3(288, 12), dim3(256), 0, stream,
        A, Bt_bf16, bihc, bhhc, gi_swz);
    hipLaunchKernelGGL(gru_kernel, dim3(12), dim3(512), 0, stream,
        gi_swz, wh16, bhhc, e_src, e_tgt, e_cmnt);

    hipLaunchKernelGGL(sim_mfma, dim3(4, 1, 64), dim3(256), 0, stream,
        e_src, e_tgt, e_cmnt, w2h, w2, src_action, tgt_action, S, rowmaxP);
    hipLaunchKernelGGL(softmax_kernel, dim3(64), dim3(256), 0, stream, rowmaxP, bw);
    hipLaunchKernelGGL(weighted_kernel, dim3(64, 8), dim3(256), 0, stream, S, bw, outSP);
    hipLaunchKernelGGL(final_kernel, dim3(1), dim3(256), 0, stream, outSP, rank_w, rank_b, out);
}